// Round 17
// baseline (32.384 us; speedup 1.0000x reference)
//
#include <hip/hip_runtime.h>

#define NCAM   6
#define FHW    72        // FH*FW
#define EMBED  128
#define NG     432       // gaussians per scale
#define THRESH 0.01f
#define AMIN   (1.0f/255.0f)
#define NTILES 891
#define TC     432
// tiles are 4 rows x 16 cols:
// s0: 7x2=14 [0,14) H=25 | s1: 13x4=52 [14,66) H=50
// s2: 25x7=175 [66,241) H=100 | s3: 50x13=650 [241,891) H=200

struct Args {
    const float* feat[4];
    const float* mean[4];
    const float* unc[4];
    const float* opac[4];
};

__device__ __forceinline__ void tile_decode(int g, int& s, int& H, int& band, int& chunk)
{
    int tb;
    if (g < 14)       { s = 0; H = 25;  tb = g;       chunk = tb & 1;  band = tb >> 1; }
    else if (g < 66)  { s = 1; H = 50;  tb = g - 14;  chunk = tb & 3;  band = tb >> 2; }
    else if (g < 241) { s = 2; H = 100; tb = g - 66;  band = tb / 7;   chunk = tb - band * 7; }
    else              { s = 3; H = 200; tb = g - 241; band = tb / 13;  chunk = tb - band * 13; }
}

// K1: [0,891) tile cull -> packed param stream; [891,915) ft transpose; 915 count
__global__ __launch_bounds__(256) void prep(Args a, float* __restrict__ ft,
                                            int* __restrict__ tlen,
                                            float4* __restrict__ p8,
                                            float* __restrict__ out)
{
    int b = blockIdx.x, t = threadIdx.x;
    if (b < NTILES) {
        __shared__ int s_cnt[8];
        int g = b;
        int s, H, band, chunk;
        tile_decode(g, s, H, band, chunk);
        int lane = t & 63, wv = t >> 6;
        float sh = H * 0.01f;
        float r0f = (float)(band * 4), r1f = (float)min(band * 4 + 3, H - 1);
        float c0f = (float)(chunk * 16), c1f = (float)min(chunk * 16 + 15, H - 1);
        const float* mean = a.mean[s];
        const float* unc  = a.unc[s];
        const float* opac = a.opac[s];

        bool v_act[2]; int v_rnk[2];
        float v_pr[2], v_pc[2], v_qa[2], v_qb[2], v_qc[2], v_ok[2];
        #pragma unroll
        for (int pp = 0; pp < 2; pp++) {
            int j = pp * 256 + t;
            bool act = false;
            float pr = 0.f, pc = 0.f, qa = 0.f, qb = 0.f, qc = 0.f, ok = 0.f;
            if (j < NG) {
                float m0 = mean[j*3+0], m1 = mean[j*3+1];
                float u00 = fmaxf(unc[j*9+0], 1.f);
                float u01 = fmaxf(unc[j*9+1], 1.f);
                float u11 = fmaxf(unc[j*9+4], 1.f);
                float op = opac[j];
                pr = -sh*m1 + H*0.5f;
                pc = -sh*m0 + H*0.5f;
                float va = sh*sh*u11 + 0.3f;
                float vb = sh*sh*u01;
                float vc = sh*sh*u00 + 0.3f;
                float det = va*vc - vb*vb;
                if (op > THRESH && det > 0.f) {
                    float inv = 1.f/det;
                    qa = 0.5f*vc*inv;                      // dr^2 coeff
                    qc = 0.5f*va*inv;                      // dc^2 coeff
                    qb = vb*inv;                           // dr*dc coeff
                    ok = op;
                    float thr = __logf(255.f*op);          // alpha >= 1/255 level set
                    float Rr = sqrtf(2.f*va*thr) + 1e-2f;  // max |dr| on level set
                    float Rc = sqrtf(2.f*vc*thr) + 1e-2f;  // max |dc| on level set
                    act = (pr >= r0f-Rr) && (pr <= r1f+Rr) &&
                          (pc >= c0f-Rc) && (pc <= c1f+Rc);
                }
            }
            unsigned long long m = __ballot(act);
            v_act[pp] = act;
            v_rnk[pp] = __popcll(m & ((1ull << lane) - 1ull));
            v_pr[pp]=pr; v_pc[pp]=pc; v_qa[pp]=qa; v_qb[pp]=qb; v_qc[pp]=qc; v_ok[pp]=ok;
            if (lane == 0) s_cnt[pp*4 + wv] = __popcll(m);
        }
        __syncthreads();
        int c8[8];
        #pragma unroll
        for (int i = 0; i < 8; i++) c8[i] = s_cnt[i];
        int len = 0;
        #pragma unroll
        for (int i = 0; i < 8; i++) len += c8[i];
        #pragma unroll
        for (int pp = 0; pp < 2; pp++) {
            int slot = pp*4 + wv;
            int pre = 0;
            #pragma unroll
            for (int i = 0; i < 8; i++) pre += (i < slot) ? c8[i] : 0;
            if (v_act[pp]) {
                int idx = g*TC + pre + v_rnk[pp];
                int j = pp * 256 + t;
                unsigned off = (unsigned)((s*NG + j) * EMBED);
                p8[idx*2 + 0] = make_float4(v_pr[pp], v_pc[pp], v_qa[pp], v_qb[pp]);
                p8[idx*2 + 1] = make_float4(v_qc[pp], v_ok[pp], __uint_as_float(off), 0.f);
            }
        }
        if (t == 0) tlen[g] = len;
    } else if (b < NTILES + 24) {
        // LDS-staged feature transpose: ft[s*NG+n][d] = feat[cam][d][hw]
        __shared__ float l[EMBED * 73];
        int sc = b - NTILES;
        int s = sc / NCAM, cam = sc - s * NCAM;
        const float* src = a.feat[s] + cam * (EMBED * FHW);
        for (int i = t; i < EMBED * FHW; i += 256) {
            int d = i / FHW, hw = i - d * FHW;
            l[d * 73 + hw] = src[i];
        }
        __syncthreads();
        float* dst = ft + (s * NG + cam * FHW) * EMBED;
        for (int e = t; e < EMBED * FHW; e += 256) {
            int hw = e >> 7, d = e & 127;
            dst[hw * EMBED + d] = l[d * 73 + hw];
        }
    } else {
        __shared__ float red[256];
        float c = 0.f;
        for (int s = 0; s < 4; s++)
            for (int i = t; i < NG; i += 256)
                c += (a.opac[s][i] > THRESH) ? 1.f : 0.f;
        red[t] = c;
        __syncthreads();
        for (int st = 128; st > 0; st >>= 1) {
            if (t < st) red[t] += red[t + st];
            __syncthreads();
        }
        if (t == 0) out[6800000] = red[0];
    }
}

// K2 hybrid:
//  blocks [0,264):  s0/s1, block=(tile,ch-quarter), 4 waves = k-quarters,
//                   prefix-T epilogue (r11-proven). Long poles first.
//  blocks [264,1089): s2/s3, block=tile, 4 waves = 4 ch-quarters, full serial
//                   scan per wave, NO LDS, NO sync, direct stores.
// No manual pipeline regs (acc[32]+params only => ~65 VGPR, TLP hides latency).
__global__ __launch_bounds__(256) void render(const float* __restrict__ ft,
                                              const int* __restrict__ tlen,
                                              const float4* __restrict__ p8,
                                              float* __restrict__ out)
{
    __shared__ float s_T[4][64];
    __shared__ float s_part[3][64][33];   // +1 pad: conflict-free scalar rows

    int bb = blockIdx.x, t = threadIdx.x;
    int lane = t & 63;
    int wv = __builtin_amdgcn_readfirstlane(t >> 6);
    int g, chq;
    bool ksplit;
    if (bb < 264) { g = bb >> 2; chq = bb & 3; ksplit = true; }
    else          { g = 66 + (bb - 264); chq = wv; ksplit = false; }

    int s, H, band, chunk;
    tile_decode(g, s, H, band, chunk);
    int P = H * H;
    float* o = out + ((s == 0) ? 0 : (s == 1) ? 80000 : (s == 2) ? 400000 : 1680000);
    int len = tlen[g];
    int k0 = 0, k1 = len;
    if (ksplit) {
        int ql = (len + 3) >> 2;
        k0 = min(wv * ql, len);
        k1 = min(k0 + ql, len);
    }
    int ch0 = chq * 32;
    const float4* pb = p8 + (size_t)(g * TC) * 2;
    int row = band*4 + (lane >> 4), col = chunk*16 + (lane & 15);
    float frow = (float)row, fcol = (float)col;

    float acc[32];
    #pragma unroll
    for (int i = 0; i < 32; i++) acc[i] = 0.f;
    float T = 1.f;

    for (int k = k0; k < k1; k++) {
        float4 A = pb[2*k];                    // wave-uniform -> scalar loads
        float4 B = pb[2*k + 1];
        float dr = A.x - frow, dc = A.y - fcol;
        float pw = A.w*dr*dc - A.z*dr*dr - B.x*dc*dc;
        float aL = 0.f;
        if (pw <= 0.f) {
            aL = fminf(B.y * __expf(pw), 0.99f);
            aL = (aL >= AMIN) ? aL : 0.f;
        }
        float w = aL * T;
        T *= (1.f - aL);
        if (__any(w > 0.f)) {
            unsigned off = __builtin_amdgcn_readfirstlane(__float_as_uint(B.z));
            const float* fr = ft + off + ch0;  // wave-uniform row
            #pragma unroll
            for (int i = 0; i < 32; i += 4) {
                float4 f = *reinterpret_cast<const float4*>(fr + i);
                acc[i]   += w * f.x; acc[i+1] += w * f.y;
                acc[i+2] += w * f.z; acc[i+3] += w * f.w;
            }
        }
        if (__all(T < 1e-5f)) break;           // saturated: residual < 1e-3
    }

    bool inb = (row < H) && (col < H);
    int pp = row * H + col;

    if (!ksplit) {
        if (inb) {
            #pragma unroll
            for (int i = 0; i < 32; i++)
                o[(ch0 + i) * P + pp] = acc[i];
        }
        return;
    }

    // ---- s0/s1 epilogue: prefix-T rescale + cross-wave reduction ----
    s_T[wv][lane] = T;
    __syncthreads();
    if (wv > 0) {
        float pref = s_T[0][lane];
        if (wv > 1) pref *= s_T[1][lane];
        if (wv > 2) pref *= s_T[2][lane];
        #pragma unroll
        for (int i = 0; i < 32; i++)
            s_part[wv-1][lane][i] = acc[i] * pref;
    }
    __syncthreads();
    if (wv == 0 && inb) {
        #pragma unroll
        for (int i = 0; i < 32; i++) {
            float v = acc[i] + s_part[0][lane][i] + s_part[1][lane][i]
                             + s_part[2][lane][i];
            o[(ch0 + i) * P + pp] = v;
        }
    }
}

extern "C" void kernel_launch(void* const* d_in, const int* in_sizes, int n_in,
                              void* d_out, int out_size, void* d_ws, size_t ws_size,
                              hipStream_t stream)
{
    Args a;
    for (int s = 0; s < 4; s++) {
        a.feat[s] = (const float*)d_in[4 * s + 0];
        a.mean[s] = (const float*)d_in[4 * s + 1];
        a.unc[s]  = (const float*)d_in[4 * s + 2];
        a.opac[s] = (const float*)d_in[4 * s + 3];
    }
    float* ws = (float*)d_ws;
    float*  ft   = ws;                                   // 221,184 floats
    int*    tlen = (int*)(ws + 221184);                  // 891 ints
    float4* p8   = (float4*)(ws + 222080);               // 891*432*2 float4 (~12.3 MB)

    prep<<<NTILES + 24 + 1, 256, 0, stream>>>(a, ft, tlen, p8, (float*)d_out);
    render<<<264 + 825, 256, 0, stream>>>(ft, tlen, p8, (float*)d_out);
}

// Round 18
// 27.121 us; speedup vs baseline: 1.1940x; 1.1940x over previous
//
#include <hip/hip_runtime.h>

#define NCAM   6
#define FHW    72        // FH*FW
#define EMBED  128
#define NG     432       // gaussians per scale
#define THRESH 0.01f
#define AMIN   (1.0f/255.0f)
#define NTILES 891
#define TC     432
// tiles are 4 rows x 16 cols:
// s0: 7x2=14 [0,14) H=25 | s1: 13x4=52 [14,66) H=50
// s2: 25x7=175 [66,241) H=100 | s3: 50x13=650 [241,891) H=200

struct Args {
    const float* feat[4];
    const float* mean[4];
    const float* unc[4];
    const float* opac[4];
};

__device__ __forceinline__ void tile_decode(int g, int& s, int& H, int& band, int& chunk)
{
    int tb;
    if (g < 14)       { s = 0; H = 25;  tb = g;       chunk = tb & 1;  band = tb >> 1; }
    else if (g < 66)  { s = 1; H = 50;  tb = g - 14;  chunk = tb & 3;  band = tb >> 2; }
    else if (g < 241) { s = 2; H = 100; tb = g - 66;  band = tb / 7;   chunk = tb - band * 7; }
    else              { s = 3; H = 200; tb = g - 241; band = tb / 13;  chunk = tb - band * 13; }
}

// K1: [0,891) tile cull -> param streams; [891,915) ft transpose; 915 count
// (verbatim from round 11 — proven, 27.07us config)
__global__ __launch_bounds__(256) void prep(Args a, float* __restrict__ ft,
                                            int* __restrict__ tlen,
                                            float4* __restrict__ p4a,
                                            float4* __restrict__ p4b,
                                            float* __restrict__ out)
{
    int b = blockIdx.x, t = threadIdx.x;
    if (b < NTILES) {
        __shared__ int s_cnt[8];
        int g = b;
        int s, H, band, chunk;
        tile_decode(g, s, H, band, chunk);
        int lane = t & 63, wv = t >> 6;
        float sh = H * 0.01f;
        float r0f = (float)(band * 4), r1f = (float)min(band * 4 + 3, H - 1);
        float c0f = (float)(chunk * 16), c1f = (float)min(chunk * 16 + 15, H - 1);
        const float* mean = a.mean[s];
        const float* unc  = a.unc[s];
        const float* opac = a.opac[s];

        bool v_act[2]; int v_rnk[2];
        float v_pr[2], v_pc[2], v_qa[2], v_qb[2], v_qc[2], v_ok[2];
        #pragma unroll
        for (int pp = 0; pp < 2; pp++) {
            int j = pp * 256 + t;
            bool act = false;
            float pr = 0.f, pc = 0.f, qa = 0.f, qb = 0.f, qc = 0.f, ok = 0.f;
            if (j < NG) {
                float m0 = mean[j*3+0], m1 = mean[j*3+1];
                float u00 = fmaxf(unc[j*9+0], 1.f);
                float u01 = fmaxf(unc[j*9+1], 1.f);
                float u11 = fmaxf(unc[j*9+4], 1.f);
                float op = opac[j];
                pr = -sh*m1 + H*0.5f;
                pc = -sh*m0 + H*0.5f;
                float va = sh*sh*u11 + 0.3f;
                float vb = sh*sh*u01;
                float vc = sh*sh*u00 + 0.3f;
                float det = va*vc - vb*vb;
                if (op > THRESH && det > 0.f) {
                    float inv = 1.f/det;
                    qa = 0.5f*vc*inv;                      // dr^2 coeff
                    qc = 0.5f*va*inv;                      // dc^2 coeff
                    qb = vb*inv;                           // dr*dc coeff
                    ok = op;
                    float thr = __logf(255.f*op);          // alpha >= 1/255 level set
                    float Rr = sqrtf(2.f*va*thr) + 1e-2f;  // max |dr| on level set
                    float Rc = sqrtf(2.f*vc*thr) + 1e-2f;  // max |dc| on level set
                    act = (pr >= r0f-Rr) && (pr <= r1f+Rr) &&
                          (pc >= c0f-Rc) && (pc <= c1f+Rc);
                }
            }
            unsigned long long m = __ballot(act);
            v_act[pp] = act;
            v_rnk[pp] = __popcll(m & ((1ull << lane) - 1ull));
            v_pr[pp]=pr; v_pc[pp]=pc; v_qa[pp]=qa; v_qb[pp]=qb; v_qc[pp]=qc; v_ok[pp]=ok;
            if (lane == 0) s_cnt[pp*4 + wv] = __popcll(m);
        }
        __syncthreads();
        int c8[8];
        #pragma unroll
        for (int i = 0; i < 8; i++) c8[i] = s_cnt[i];
        int len = 0;
        #pragma unroll
        for (int i = 0; i < 8; i++) len += c8[i];
        #pragma unroll
        for (int pp = 0; pp < 2; pp++) {
            int slot = pp*4 + wv;
            int pre = 0;
            #pragma unroll
            for (int i = 0; i < 8; i++) pre += (i < slot) ? c8[i] : 0;
            if (v_act[pp]) {
                int idx = g*TC + pre + v_rnk[pp];
                int j = pp * 256 + t;
                unsigned off = (unsigned)((s*NG + j) * EMBED);
                p4a[idx] = make_float4(v_pr[pp], v_pc[pp], v_qa[pp], v_qb[pp]);
                p4b[idx] = make_float4(v_qc[pp], v_ok[pp], __uint_as_float(off), 0.f);
            }
        }
        if (t == 0) tlen[g] = len;
    } else if (b < NTILES + 24) {
        // LDS-staged feature transpose: ft[s*NG+n][d] = feat[cam][d][hw]
        __shared__ float l[EMBED * 73];
        int sc = b - NTILES;
        int s = sc / NCAM, cam = sc - s * NCAM;
        const float* src = a.feat[s] + cam * (EMBED * FHW);
        for (int i = t; i < EMBED * FHW; i += 256) {
            int d = i / FHW, hw = i - d * FHW;
            l[d * 73 + hw] = src[i];
        }
        __syncthreads();
        float* dst = ft + (s * NG + cam * FHW) * EMBED;
        for (int e = t; e < EMBED * FHW; e += 256) {
            int hw = e >> 7, d = e & 127;
            dst[hw * EMBED + d] = l[d * 73 + hw];
        }
    } else {
        __shared__ float red[256];
        float c = 0.f;
        for (int s = 0; s < 4; s++)
            for (int i = t; i < NG; i += 256)
                c += (a.opac[s][i] > THRESH) ? 1.f : 0.f;
        red[t] = c;
        __syncthreads();
        for (int st = 128; st > 0; st >>= 1) {
            if (t < st) red[t] += red[t + st];
            __syncthreads();
        }
        if (t == 0) out[6800000] = red[0];
    }
}

// K2: r11 structure (block=(tile,ch-quarter), 4 waves = k-quarters, lane=px,
// register-only alpha/T/acc, no hot-loop LDS/sync) with ONE change: loop-order
// surgery. A,B carried in registers dist-1, so per iteration:
//   1. feature loads for k issue at cycle 0 (address from resident B)
//   2. param loads for k+1 issue right behind
//   3. alpha computes from resident A,B while loads fly
//   4. FMAs consume features as they return
// Exposed chain ~450cy -> ~150-200cy; same instruction count; ~+16 VGPR.
__global__ __launch_bounds__(256) void render(const float* __restrict__ ft,
                                              const int* __restrict__ tlen,
                                              const float4* __restrict__ p4a,
                                              const float4* __restrict__ p4b,
                                              float* __restrict__ out)
{
    __shared__ float s_T[4][64];
    __shared__ float s_part[3][64][33];   // +1 pad: conflict-free scalar rows

    int bb = blockIdx.x, t = threadIdx.x;
    int g = bb >> 2, chq = bb & 3;
    int s, H, band, chunk;
    tile_decode(g, s, H, band, chunk);
    int P = H * H;
    float* o = out + ((s == 0) ? 0 : (s == 1) ? 80000 : (s == 2) ? 400000 : 1680000);
    int lane = t & 63;
    int wv = __builtin_amdgcn_readfirstlane(t >> 6);
    int ch0 = chq * 32;
    int len = tlen[g];
    int qlen = (len + 3) >> 2;
    int k0 = wv * qlen, k1 = min(k0 + qlen, len);
    int base = g * TC;
    int row = band*4 + (lane >> 4), col = chunk*16 + (lane & 15);
    float frow = (float)row, fcol = (float)col;

    float acc[32];
    #pragma unroll
    for (int i = 0; i < 32; i++) acc[i] = 0.f;
    float T = 1.f;

    if (k0 < k1) {
        float4 A = p4a[base + k0];            // prologue: params for k0
        float4 B = p4b[base + k0];
        for (int k = k0; k < k1; k++) {
            // (1) feature loads for k — address from RESIDENT B, issue first
            unsigned off = __builtin_amdgcn_readfirstlane(__float_as_uint(B.z));
            const float* fr = ft + off + ch0;
            float4 f0 = *reinterpret_cast<const float4*>(fr);
            float4 f1 = *reinterpret_cast<const float4*>(fr + 4);
            float4 f2 = *reinterpret_cast<const float4*>(fr + 8);
            float4 f3 = *reinterpret_cast<const float4*>(fr + 12);
            float4 f4 = *reinterpret_cast<const float4*>(fr + 16);
            float4 f5 = *reinterpret_cast<const float4*>(fr + 20);
            float4 f6 = *reinterpret_cast<const float4*>(fr + 24);
            float4 f7 = *reinterpret_cast<const float4*>(fr + 28);
            // (2) param loads for k+1 — in flight across this iteration
            int kn = (k + 1 < k1) ? k + 1 : k;
            float4 An = p4a[base + kn];
            float4 Bn = p4b[base + kn];
            // (3) alpha from resident A,B — covers load flight time
            float dr = A.x - frow, dc = A.y - fcol;
            float pw = A.w*dr*dc - A.z*dr*dr - B.x*dc*dc;
            float aL = 0.f;
            if (pw <= 0.f) {
                aL = fminf(B.y * __expf(pw), 0.99f);
                aL = (aL >= AMIN) ? aL : 0.f;
            }
            float w = aL * T;
            T *= (1.f - aL);
            // (4) FMAs consume features as they return
            acc[0]  += w * f0.x; acc[1]  += w * f0.y; acc[2]  += w * f0.z; acc[3]  += w * f0.w;
            acc[4]  += w * f1.x; acc[5]  += w * f1.y; acc[6]  += w * f1.z; acc[7]  += w * f1.w;
            acc[8]  += w * f2.x; acc[9]  += w * f2.y; acc[10] += w * f2.z; acc[11] += w * f2.w;
            acc[12] += w * f3.x; acc[13] += w * f3.y; acc[14] += w * f3.z; acc[15] += w * f3.w;
            acc[16] += w * f4.x; acc[17] += w * f4.y; acc[18] += w * f4.z; acc[19] += w * f4.w;
            acc[20] += w * f5.x; acc[21] += w * f5.y; acc[22] += w * f5.z; acc[23] += w * f5.w;
            acc[24] += w * f6.x; acc[25] += w * f6.y; acc[26] += w * f6.z; acc[27] += w * f6.w;
            acc[28] += w * f7.x; acc[29] += w * f7.y; acc[30] += w * f7.z; acc[31] += w * f7.w;
            A = An; B = Bn;
        }
    }

    // ---- epilogue: prefix-T rescale + cross-wave reduction (r11 verbatim) ----
    s_T[wv][lane] = T;
    __syncthreads();
    if (wv > 0) {
        float pref = s_T[0][lane];
        if (wv > 1) pref *= s_T[1][lane];
        if (wv > 2) pref *= s_T[2][lane];
        #pragma unroll
        for (int i = 0; i < 32; i++)
            s_part[wv-1][lane][i] = acc[i] * pref;
    }
    __syncthreads();
    if (wv == 0 && row < H && col < H) {
        int pp = row * H + col;
        #pragma unroll
        for (int i = 0; i < 32; i++) {
            float v = acc[i] + s_part[0][lane][i] + s_part[1][lane][i]
                             + s_part[2][lane][i];
            o[(ch0 + i) * P + pp] = v;
        }
    }
}

extern "C" void kernel_launch(void* const* d_in, const int* in_sizes, int n_in,
                              void* d_out, int out_size, void* d_ws, size_t ws_size,
                              hipStream_t stream)
{
    Args a;
    for (int s = 0; s < 4; s++) {
        a.feat[s] = (const float*)d_in[4 * s + 0];
        a.mean[s] = (const float*)d_in[4 * s + 1];
        a.unc[s]  = (const float*)d_in[4 * s + 2];
        a.opac[s] = (const float*)d_in[4 * s + 3];
    }
    float* ws = (float*)d_ws;
    float*  ft   = ws;                                   // 221,184 floats
    int*    tlen = (int*)(ws + 221184);                  // 891 ints
    float4* p4a  = (float4*)(ws + 222080);               // 891*432 float4
    float4* p4b  = p4a + NTILES * TC;                    // 891*432 float4

    prep<<<NTILES + 24 + 1, 256, 0, stream>>>(a, ft, tlen, p4a, p4b, (float*)d_out);
    render<<<NTILES * 4, 256, 0, stream>>>(ft, tlen, p4a, p4b, (float*)d_out);
}